// Round 5
// baseline (14.888 us; speedup 1.0000x reference)
//
#include <hip/hip_runtime.h>

#define LOOKBACK 8
#define HID 32
#define TB 128                 // threads per block
#define TPB 256                // t's per block (2 per thread)
#define NR  (TPB + LOOKBACK)   // 264 K rows per block
#define EPS 1e-6f

// sP (LDS) param layout (floats)
#define WS_AQ  0     // [4][32]
#define WS_CQ  128   // [32]
#define WS_AK  160   // [4][32]
#define WS_CK  288   // [32]
#define WS_AVW 320   // [4]
#define WS_CVW 324   // scalar
#define WS_N   336

// K storage: per-g region; each row = 4 floats (16B), 16B pad every 8 rows.
// off(g,row) = g*GSZ + row*4 + (row>>3)*4  (floats). Stride-1 and stride-2
// row access both land at the 8-access/bank floor.
#define GSZ 1188   // 264*4 + 33*4

__device__ __forceinline__ float phi1(float z) {
    return (z >= 0.0f ? z : 0.01f * z) + 1.0f;
}
__device__ __forceinline__ float dot4(const float4 a, const float4 b) {
    return a.x*b.x + a.y*b.y + a.z*b.z + a.w*b.w;
}

__global__ __launch_bounds__(TB) void ga_fused(
    const float* __restrict__ x,            // (B, L, 4)
    const float* __restrict__ sbp, const float* __restrict__ vsp,
    const float* __restrict__ vbp, const float* __restrict__ bwp,
    const float* __restrict__ WQ,  const float* __restrict__ WK,
    const float* __restrict__ WV,  const float* __restrict__ wh,
    const float* __restrict__ bhp,
    float* __restrict__ out,                // pred (B*T) then weights (B*T*8)
    int B, int L)
{
    const int T   = L - LOOKBACK;
    const int bb  = blockIdx.y;
    const int t0  = blockIdx.x * TPB;
    const int tid = threadIdx.x;

    __shared__ float sP[WS_N];
    __shared__ float sK[8 * GSZ];
    __shared__ float sVW[NR];

    const float* xb = x + (size_t)bb * L * 4;

    // ---- prefetch queries for this thread's t-pair (hides under collapse/A) ----
    const int tl = 2 * tid;               // local t base
    const int ta = t0 + tl;
    const bool va = (ta < T);
    const bool vb = (ta + 1 < T);
    const float4 xqa = *reinterpret_cast<const float4*>(
        xb + (size_t)(va ? ta + LOOKBACK : 0) * 4);
    const float4 xqb = *reinterpret_cast<const float4*>(
        xb + (size_t)(vb ? ta + 1 + LOOKBACK : 0) * 4);

    // ---- Phase 0: in-block parameter collapse (threads 0..95) ----
    if (tid < 96) {
        const int h   = tid & 31;
        const int mat = tid >> 5;          // 0=Q, 1=K, 2=V
        const float* W = (mat == 0) ? WQ : (mat == 1) ? WK : WV;
        float w[11];
#pragma unroll
        for (int j = 0; j < 11; ++j) w[j] = W[j * HID + h];

        const float b0 = bwp[0], b1 = bwp[1], b2 = bwp[2];
        const float b3 = bwp[3], b4 = bwp[4], b5 = bwp[5];
        const float v0 = vsp[0], v1 = vsp[1], v2 = vsp[2], v3 = vsp[3];
        const float u0 = vbp[0], u1 = vbp[1], u2 = vbp[2], u3 = vbp[3];
        const float s0 = 1.0f + sbp[0];

        const float a0 = v0*w[1] + b0*w[5] + b1*w[6] + b2*w[7];
        const float a1 = v1*w[2] - b0*w[5] + b3*w[8] + b4*w[9];
        const float a2 = v2*w[3] - b1*w[6] - b3*w[8] + b5*w[10];
        const float a3 = v3*w[4] - b2*w[7] - b4*w[9] - b5*w[10];
        const float c  = s0*w[0] + u0*w[1] + u1*w[2] + u2*w[3] + u3*w[4];

        if (mat == 0) {
            sP[WS_AQ + 0*HID + h] = a0; sP[WS_AQ + 1*HID + h] = a1;
            sP[WS_AQ + 2*HID + h] = a2; sP[WS_AQ + 3*HID + h] = a3;
            sP[WS_CQ + h] = c;
        } else if (mat == 1) {
            sP[WS_AK + 0*HID + h] = a0; sP[WS_AK + 1*HID + h] = a1;
            sP[WS_AK + 2*HID + h] = a2; sP[WS_AK + 3*HID + h] = a3;
            sP[WS_CK + h] = c;
        } else {
            const float ww = wh[h];
            float r[5] = { a0*ww, a1*ww, a2*ww, a3*ww, c*ww };
#pragma unroll
            for (int off = 16; off > 0; off >>= 1) {
#pragma unroll
                for (int i = 0; i < 5; ++i) r[i] += __shfl_down(r[i], off, 32);
            }
            if (h == 0) {
                sP[WS_AVW + 0] = r[0]; sP[WS_AVW + 1] = r[1];
                sP[WS_AVW + 2] = r[2]; sP[WS_AVW + 3] = r[3];
                sP[WS_CVW]     = r[4];
            }
        }
    }
    __syncthreads();

    // ---- Phase A: K rows (per-g layout) + V.w_head ----
    const int npos = min(NR, L - t0);   // always >= 256
    const int r0 = tid, r1 = tid + TB;
    const bool has2 = (tid + 2*TB < npos);
    const int r2 = tid + 2*TB;

    const float4 x0 = *reinterpret_cast<const float4*>(xb + (size_t)(t0 + r0) * 4);
    const float4 x1 = *reinterpret_cast<const float4*>(xb + (size_t)(t0 + r1) * 4);
    const float4 x2 = *reinterpret_cast<const float4*>(
        xb + (size_t)(has2 ? t0 + r2 : t0) * 4);

    {
        const float avw0 = sP[WS_AVW + 0], avw1 = sP[WS_AVW + 1];
        const float avw2 = sP[WS_AVW + 2], avw3 = sP[WS_AVW + 3];
        const float cvw  = sP[WS_CVW];
        sVW[r0] = cvw + x0.x*avw0 + x0.y*avw1 + x0.z*avw2 + x0.w*avw3;
        sVW[r1] = cvw + x1.x*avw0 + x1.y*avw1 + x1.z*avw2 + x1.w*avw3;
        if (has2)
            sVW[r2] = cvw + x2.x*avw0 + x2.y*avw1 + x2.z*avw2 + x2.w*avw3;
    }

    const int o0 = r0*4 + (r0>>3)*4;
    const int o1 = r1*4 + (r1>>3)*4;
    const int o2 = r2*4 + (r2>>3)*4;

#pragma unroll
    for (int g = 0; g < 8; ++g) {
        const float4 c  = *reinterpret_cast<const float4*>(&sP[WS_CK + g*4]);
        const float4 a0 = *reinterpret_cast<const float4*>(&sP[WS_AK + 0*HID + g*4]);
        const float4 a1 = *reinterpret_cast<const float4*>(&sP[WS_AK + 1*HID + g*4]);
        const float4 a2 = *reinterpret_cast<const float4*>(&sP[WS_AK + 2*HID + g*4]);
        const float4 a3 = *reinterpret_cast<const float4*>(&sP[WS_AK + 3*HID + g*4]);

        float4 k;
        k.x = c.x + x0.x*a0.x + x0.y*a1.x + x0.z*a2.x + x0.w*a3.x;
        k.y = c.y + x0.x*a0.y + x0.y*a1.y + x0.z*a2.y + x0.w*a3.y;
        k.z = c.z + x0.x*a0.z + x0.y*a1.z + x0.z*a2.z + x0.w*a3.z;
        k.w = c.w + x0.x*a0.w + x0.y*a1.w + x0.z*a2.w + x0.w*a3.w;
        k.x = phi1(k.x); k.y = phi1(k.y); k.z = phi1(k.z); k.w = phi1(k.w);
        *reinterpret_cast<float4*>(&sK[g*GSZ + o0]) = k;

        k.x = c.x + x1.x*a0.x + x1.y*a1.x + x1.z*a2.x + x1.w*a3.x;
        k.y = c.y + x1.x*a0.y + x1.y*a1.y + x1.z*a2.y + x1.w*a3.y;
        k.z = c.z + x1.x*a0.z + x1.y*a1.z + x1.z*a2.z + x1.w*a3.z;
        k.w = c.w + x1.x*a0.w + x1.y*a1.w + x1.z*a2.w + x1.w*a3.w;
        k.x = phi1(k.x); k.y = phi1(k.y); k.z = phi1(k.z); k.w = phi1(k.w);
        *reinterpret_cast<float4*>(&sK[g*GSZ + o1]) = k;

        if (has2) {
            k.x = c.x + x2.x*a0.x + x2.y*a1.x + x2.z*a2.x + x2.w*a3.x;
            k.y = c.y + x2.x*a0.y + x2.y*a1.y + x2.z*a2.y + x2.w*a3.y;
            k.z = c.z + x2.x*a0.z + x2.y*a1.z + x2.z*a2.z + x2.w*a3.z;
            k.w = c.w + x2.x*a0.w + x2.y*a1.w + x2.z*a2.w + x2.w*a3.w;
            k.x = phi1(k.x); k.y = phi1(k.y); k.z = phi1(k.z); k.w = phi1(k.w);
            *reinterpret_cast<float4*>(&sK[g*GSZ + o2]) = k;
        }
    }
    __syncthreads();

    // ---- Phase B: t-pair, per-g interleaved q + window dots ----
    if (!va) return;

    float scA[LOOKBACK], scB[LOOKBACK];
#pragma unroll
    for (int l = 0; l < LOOKBACK; ++l) { scA[l] = 0.0f; scB[l] = 0.0f; }

    // row byte-offsets for rows tl .. tl+8 (independent of g)
    int ro[9];
#pragma unroll
    for (int j = 0; j < 9; ++j) {
        const int r = tl + j;
        ro[j] = r*4 + (r>>3)*4;
    }

#pragma unroll
    for (int g = 0; g < 8; ++g) {
        const float4 cq = *reinterpret_cast<const float4*>(&sP[WS_CQ + g*4]);
        const float4 a0 = *reinterpret_cast<const float4*>(&sP[WS_AQ + 0*HID + g*4]);
        const float4 a1 = *reinterpret_cast<const float4*>(&sP[WS_AQ + 1*HID + g*4]);
        const float4 a2 = *reinterpret_cast<const float4*>(&sP[WS_AQ + 2*HID + g*4]);
        const float4 a3 = *reinterpret_cast<const float4*>(&sP[WS_AQ + 3*HID + g*4]);

        float4 qa, qb;
        qa.x = phi1(cq.x + xqa.x*a0.x + xqa.y*a1.x + xqa.z*a2.x + xqa.w*a3.x);
        qa.y = phi1(cq.y + xqa.x*a0.y + xqa.y*a1.y + xqa.z*a2.y + xqa.w*a3.y);
        qa.z = phi1(cq.z + xqa.x*a0.z + xqa.y*a1.z + xqa.z*a2.z + xqa.w*a3.z);
        qa.w = phi1(cq.w + xqa.x*a0.w + xqa.y*a1.w + xqa.z*a2.w + xqa.w*a3.w);
        qb.x = phi1(cq.x + xqb.x*a0.x + xqb.y*a1.x + xqb.z*a2.x + xqb.w*a3.x);
        qb.y = phi1(cq.y + xqb.x*a0.y + xqb.y*a1.y + xqb.z*a2.y + xqb.w*a3.y);
        qb.z = phi1(cq.z + xqb.x*a0.z + xqb.y*a1.z + xqb.z*a2.z + xqb.w*a3.z);
        qb.w = phi1(cq.w + xqb.x*a0.w + xqb.y*a1.w + xqb.z*a2.w + xqb.w*a3.w);

        const float* kg = &sK[g * GSZ];
        float4 k0 = *reinterpret_cast<const float4*>(kg + ro[0]);
        float4 k1 = *reinterpret_cast<const float4*>(kg + ro[1]);
        float4 k2 = *reinterpret_cast<const float4*>(kg + ro[2]);
        float4 k3 = *reinterpret_cast<const float4*>(kg + ro[3]);
        float4 k4 = *reinterpret_cast<const float4*>(kg + ro[4]);
        float4 k5 = *reinterpret_cast<const float4*>(kg + ro[5]);
        float4 k6 = *reinterpret_cast<const float4*>(kg + ro[6]);
        float4 k7 = *reinterpret_cast<const float4*>(kg + ro[7]);
        float4 k8 = *reinterpret_cast<const float4*>(kg + ro[8]);

        scA[0] += dot4(qa, k0); scB[0] += dot4(qb, k1);
        scA[1] += dot4(qa, k1); scB[1] += dot4(qb, k2);
        scA[2] += dot4(qa, k2); scB[2] += dot4(qb, k3);
        scA[3] += dot4(qa, k3); scB[3] += dot4(qb, k4);
        scA[4] += dot4(qa, k4); scB[4] += dot4(qb, k5);
        scA[5] += dot4(qa, k5); scB[5] += dot4(qb, k6);
        scA[6] += dot4(qa, k6); scB[6] += dot4(qb, k7);
        scA[7] += dot4(qa, k7); scB[7] += dot4(qb, k8);
    }

    const float bh = bhp[0];
    float ssA = 0.0f, pA = 0.0f, ssB = 0.0f, pB = 0.0f;
#pragma unroll
    for (int l = 0; l < LOOKBACK; ++l) {
        ssA += scA[l];  pA += scA[l] * sVW[tl + l];
        ssB += scB[l];  pB += scB[l] * sVW[tl + 1 + l];
    }
    const float invA = 1.0f / (ssA + EPS);
    const float invB = 1.0f / (ssB + EPS);

    out[(size_t)bb * T + ta] = pA * invA + bh;
    float* wA = out + (size_t)B * T + ((size_t)bb * T + ta) * LOOKBACK;
    *reinterpret_cast<float4*>(wA) =
        make_float4(scA[0]*invA, scA[1]*invA, scA[2]*invA, scA[3]*invA);
    *reinterpret_cast<float4*>(wA + 4) =
        make_float4(scA[4]*invA, scA[5]*invA, scA[6]*invA, scA[7]*invA);

    if (vb) {
        out[(size_t)bb * T + ta + 1] = pB * invB + bh;
        float* wB = wA + LOOKBACK;
        *reinterpret_cast<float4*>(wB) =
            make_float4(scB[0]*invB, scB[1]*invB, scB[2]*invB, scB[3]*invB);
        *reinterpret_cast<float4*>(wB + 4) =
            make_float4(scB[4]*invB, scB[5]*invB, scB[6]*invB, scB[7]*invB);
    }
}

extern "C" void kernel_launch(void* const* d_in, const int* in_sizes, int n_in,
                              void* d_out, int out_size, void* d_ws, size_t ws_size,
                              hipStream_t stream) {
    const float* x  = (const float*)d_in[0];
    const float* sb = (const float*)d_in[1];
    const float* vs = (const float*)d_in[2];
    const float* vb = (const float*)d_in[3];
    const float* bw = (const float*)d_in[4];
    const float* WQ = (const float*)d_in[5];
    const float* WK = (const float*)d_in[6];
    const float* WV = (const float*)d_in[7];
    const float* wh = (const float*)d_in[8];
    const float* bh = (const float*)d_in[9];
    float* out = (float*)d_out;

    // in_sizes[0] = B*L*4 ; out_size = B*(L-LOOKBACK)*(1+LOOKBACK)
    const long long bl = (long long)in_sizes[0] / 4;            // B*L
    const long long bt = (long long)out_size / (1 + LOOKBACK);  // B*(L-8)
    const int B = (int)((bl - bt) / LOOKBACK);
    const int L = (int)(bl / B);
    const int T = L - LOOKBACK;

    dim3 grid((T + TPB - 1) / TPB, B);
    ga_fused<<<grid, TB, 0, stream>>>(x, sb, vs, vb, bw, WQ, WK, WV, wh, bh,
                                      out, B, L);
}

// Round 6
// 13.420 us; speedup vs baseline: 1.1094x; 1.1094x over previous
//
#include <hip/hip_runtime.h>
#include <hip/hip_bf16.h>

#define LOOKBACK 8
#define HID 32
#define TB 256                 // threads per block == t's per block
#define NR  (TB + LOOKBACK)    // 264 K rows per block
#define RST 20                 // uints per K row (16 used + 4 pad) = 80B stride
#define EPS 1e-6f

// sP (LDS) param layout (floats)
#define WS_AQ  0     // [4][32]
#define WS_CQ  128   // [32]
#define WS_AK  160   // [4][32]
#define WS_CK  288   // [32]
#define WS_AVW 320   // [4]
#define WS_CVW 324   // scalar
#define WS_N   336

__device__ __forceinline__ float phi1(float z) {
    return (z >= 0.0f ? z : 0.01f * z) + 1.0f;
}
__device__ __forceinline__ unsigned pack_bf16(float a, float b) {
    __hip_bfloat162 h = __float22bfloat162_rn(make_float2(a, b));
    return *reinterpret_cast<unsigned*>(&h);
}
__device__ __forceinline__ float blo(unsigned u) {   // element packed first (ch 2m)
    return __uint_as_float(u << 16);
}
__device__ __forceinline__ float bhi(unsigned u) {   // ch 2m+1
    return __uint_as_float(u & 0xffff0000u);
}

__global__ __launch_bounds__(TB) void ga_fused(
    const float* __restrict__ x,            // (B, L, 4)
    const float* __restrict__ sbp, const float* __restrict__ vsp,
    const float* __restrict__ vbp, const float* __restrict__ bwp,
    const float* __restrict__ WQ,  const float* __restrict__ WK,
    const float* __restrict__ WV,  const float* __restrict__ wh,
    const float* __restrict__ bhp,
    float* __restrict__ out,                // pred (B*T) then weights (B*T*8)
    int B, int L)
{
    const int T   = L - LOOKBACK;
    const int bb  = blockIdx.y;
    const int t0  = blockIdx.x * TB;
    const int tid = threadIdx.x;

    __shared__ float    sP[WS_N];
    __shared__ unsigned sK[NR * RST];       // bf16-packed K rows
    __shared__ float    sVW[NR];

    const float* xb = x + (size_t)bb * L * 4;

    // ---- prefetch this thread's query x (hides under collapse + phase A) ----
    const int t = t0 + tid;
    const bool valid = (t < T);
    const float4 xq = *reinterpret_cast<const float4*>(
        xb + (size_t)(valid ? t + LOOKBACK : 0) * 4);

    // ---- Phase 0: in-block parameter collapse (threads 0..95) ----
    if (tid < 96) {
        const int h   = tid & 31;
        const int mat = tid >> 5;          // 0=Q, 1=K, 2=V
        const float* W = (mat == 0) ? WQ : (mat == 1) ? WK : WV;
        float w[11];
#pragma unroll
        for (int j = 0; j < 11; ++j) w[j] = W[j * HID + h];

        const float b0 = bwp[0], b1 = bwp[1], b2 = bwp[2];
        const float b3 = bwp[3], b4 = bwp[4], b5 = bwp[5];
        const float v0 = vsp[0], v1 = vsp[1], v2 = vsp[2], v3 = vsp[3];
        const float u0 = vbp[0], u1 = vbp[1], u2 = vbp[2], u3 = vbp[3];
        const float s0 = 1.0f + sbp[0];

        // x_d coefficients. BIV_I=[0,0,0,1,1,2], BIV_J=[1,2,3,2,3,3]
        const float a0 = v0*w[1] + b0*w[5] + b1*w[6] + b2*w[7];
        const float a1 = v1*w[2] - b0*w[5] + b3*w[8] + b4*w[9];
        const float a2 = v2*w[3] - b1*w[6] - b3*w[8] + b5*w[10];
        const float a3 = v3*w[4] - b2*w[7] - b4*w[9] - b5*w[10];
        const float c  = s0*w[0] + u0*w[1] + u1*w[2] + u2*w[3] + u3*w[4];

        if (mat == 0) {
            sP[WS_AQ + 0*HID + h] = a0; sP[WS_AQ + 1*HID + h] = a1;
            sP[WS_AQ + 2*HID + h] = a2; sP[WS_AQ + 3*HID + h] = a3;
            sP[WS_CQ + h] = c;
        } else if (mat == 1) {
            sP[WS_AK + 0*HID + h] = a0; sP[WS_AK + 1*HID + h] = a1;
            sP[WS_AK + 2*HID + h] = a2; sP[WS_AK + 3*HID + h] = a3;
            sP[WS_CK + h] = c;
        } else {
            const float ww = wh[h];
            float r[5] = { a0*ww, a1*ww, a2*ww, a3*ww, c*ww };
#pragma unroll
            for (int off = 16; off > 0; off >>= 1) {
#pragma unroll
                for (int i = 0; i < 5; ++i) r[i] += __shfl_down(r[i], off, 32);
            }
            if (h == 0) {
                sP[WS_AVW + 0] = r[0]; sP[WS_AVW + 1] = r[1];
                sP[WS_AVW + 2] = r[2]; sP[WS_AVW + 3] = r[3];
                sP[WS_CVW]     = r[4];
            }
        }
    }
    __syncthreads();

    // ---- Phase A: bf16 K rows + V.w_head ----
    const float avw0 = sP[WS_AVW + 0], avw1 = sP[WS_AVW + 1];
    const float avw2 = sP[WS_AVW + 2], avw3 = sP[WS_AVW + 3];
    const float cvw  = sP[WS_CVW];

    const int npos = min(NR, L - t0);
    for (int r = tid; r < npos; r += TB) {
        const float4 xv = *reinterpret_cast<const float4*>(xb + (size_t)(t0 + r) * 4);

        sVW[r] = cvw + xv.x*avw0 + xv.y*avw1 + xv.z*avw2 + xv.w*avw3;

        unsigned u[16];
#pragma unroll
        for (int g = 0; g < 8; ++g) {
            float4 a = *reinterpret_cast<const float4*>(&sP[WS_CK + g*4]);
#pragma unroll
            for (int d = 0; d < 4; ++d) {
                const float xd = (d == 0) ? xv.x : (d == 1) ? xv.y
                               : (d == 2) ? xv.z : xv.w;
                const float4 ad = *reinterpret_cast<const float4*>(
                    &sP[WS_AK + d*HID + g*4]);
                a.x += xd*ad.x; a.y += xd*ad.y; a.z += xd*ad.z; a.w += xd*ad.w;
            }
            a.x = phi1(a.x); a.y = phi1(a.y); a.z = phi1(a.z); a.w = phi1(a.w);
            u[2*g]   = pack_bf16(a.x, a.y);
            u[2*g+1] = pack_bf16(a.z, a.w);
        }
        unsigned* dst = &sK[r * RST];
        *reinterpret_cast<uint4*>(dst + 0)  = make_uint4(u[0],  u[1],  u[2],  u[3]);
        *reinterpret_cast<uint4*>(dst + 4)  = make_uint4(u[4],  u[5],  u[6],  u[7]);
        *reinterpret_cast<uint4*>(dst + 8)  = make_uint4(u[8],  u[9],  u[10], u[11]);
        *reinterpret_cast<uint4*>(dst + 12) = make_uint4(u[12], u[13], u[14], u[15]);
    }
    __syncthreads();

    // ---- Phase B: per-thread q (f32), 8 window dots vs bf16 K ----
    if (!valid) return;

    float q[HID];
#pragma unroll
    for (int g = 0; g < 8; ++g) {
        float4 z = *reinterpret_cast<const float4*>(&sP[WS_CQ + g*4]);
#pragma unroll
        for (int d = 0; d < 4; ++d) {
            const float xd = (d == 0) ? xq.x : (d == 1) ? xq.y
                           : (d == 2) ? xq.z : xq.w;
            const float4 ad = *reinterpret_cast<const float4*>(
                &sP[WS_AQ + d*HID + g*4]);
            z.x += xd*ad.x; z.y += xd*ad.y; z.z += xd*ad.z; z.w += xd*ad.w;
        }
        q[g*4+0] = phi1(z.x); q[g*4+1] = phi1(z.y);
        q[g*4+2] = phi1(z.z); q[g*4+3] = phi1(z.w);
    }

    float sc[LOOKBACK];
#pragma unroll
    for (int l = 0; l < LOOKBACK; ++l) {
        const unsigned* kr = &sK[(tid + l) * RST];
        float s = 0.0f;
#pragma unroll
        for (int g = 0; g < 4; ++g) {
            const uint4 w = *reinterpret_cast<const uint4*>(kr + 4*g);
            const int c0 = 8 * g;
            s += blo(w.x)*q[c0+0] + bhi(w.x)*q[c0+1]
               + blo(w.y)*q[c0+2] + bhi(w.y)*q[c0+3]
               + blo(w.z)*q[c0+4] + bhi(w.z)*q[c0+5]
               + blo(w.w)*q[c0+6] + bhi(w.w)*q[c0+7];
        }
        sc[l] = s;
    }

    float ssum = 0.0f, p = 0.0f;
#pragma unroll
    for (int l = 0; l < LOOKBACK; ++l) {
        ssum += sc[l];
        p    += sc[l] * sVW[tid + l];
    }
    const float inv = 1.0f / (ssum + EPS);

    out[(size_t)bb * T + t] = p * inv + bhp[0];

    float* wout = out + (size_t)B * T + ((size_t)bb * T + t) * LOOKBACK;
    *reinterpret_cast<float4*>(wout) =
        make_float4(sc[0]*inv, sc[1]*inv, sc[2]*inv, sc[3]*inv);
    *reinterpret_cast<float4*>(wout + 4) =
        make_float4(sc[4]*inv, sc[5]*inv, sc[6]*inv, sc[7]*inv);
}

extern "C" void kernel_launch(void* const* d_in, const int* in_sizes, int n_in,
                              void* d_out, int out_size, void* d_ws, size_t ws_size,
                              hipStream_t stream) {
    const float* x  = (const float*)d_in[0];
    const float* sb = (const float*)d_in[1];
    const float* vs = (const float*)d_in[2];
    const float* vb = (const float*)d_in[3];
    const float* bw = (const float*)d_in[4];
    const float* WQ = (const float*)d_in[5];
    const float* WK = (const float*)d_in[6];
    const float* WV = (const float*)d_in[7];
    const float* wh = (const float*)d_in[8];
    const float* bh = (const float*)d_in[9];
    float* out = (float*)d_out;

    // in_sizes[0] = B*L*4 ; out_size = B*(L-LOOKBACK)*(1+LOOKBACK)
    const long long bl = (long long)in_sizes[0] / 4;            // B*L
    const long long bt = (long long)out_size / (1 + LOOKBACK);  // B*(L-8)
    const int B = (int)((bl - bt) / LOOKBACK);
    const int L = (int)(bl / B);
    const int T = L - LOOKBACK;

    dim3 grid((T + TB - 1) / TB, B);
    ga_fused<<<grid, TB, 0, stream>>>(x, sb, vs, vb, bw, WQ, WK, WV, wh, bh,
                                      out, B, L);
}